// Round 6
// baseline (386.281 us; speedup 1.0000x reference)
//
#include <hip/hip_runtime.h>
#include <stdint.h>

// ESN fused v8: symmetric self-contained waves.
//   grid 256 = 32 b x 8 strips (PB=128/block); block = 128 thr = 2 waves.
//   Each wave owns 64 p end-to-end: GEMM(96 MFMA) + private pT + scan + coalesced
//   writeout. Waves share only uB staging -> ONE symmetric barrier per chunk.
//   Scan chain stalls are filled by same-wave GEMM/pack/writeout work (ILP, not TLP).
// B=32, D_IN=64, D_STATE=1024, L=2048, LEAK=0.5
#define B_   32
#define H_   64
#define P_   1024
#define L_   2048
#define TL   64
#define PB   128   // p per block
#define PBW  64    // p per wave
#define NCH  (L_ / TL)
#define UST  68    // uB row stride in u32 (row = 272 B, 16B-aligned)
#define PST  68    // pT row stride in f32

#define TWO_LOG2E 2.88539008177792681472f

typedef __attribute__((ext_vector_type(8))) short short8;
typedef __attribute__((ext_vector_type(4))) float f32x4;
typedef __attribute__((ext_vector_type(4))) int   i32x4;

// lowers to v_exp_f32 (hardware exp2)
#define EXP2(x) __builtin_exp2f(x)

__device__ __forceinline__ short8 as_short8(i32x4 v) {
    union { i32x4 i; short8 s; } u; u.i = v; return u.s;
}

// f = hi(bf16, trunc) + lo(bf16, RNE of remainder); packed as hi | lo<<16
__device__ __forceinline__ unsigned pack_hilo(float f) {
    unsigned ub = __float_as_uint(f);
    float    fh = __uint_as_float(ub & 0xFFFF0000u);
    float    rm = f - fh;                       // exact
    unsigned r  = __float_as_uint(rm);
    r += 0x7FFFu + ((r >> 16) & 1u);            // RNE to bf16
    return (ub >> 16) | (r & 0xFFFF0000u);
}

__global__ __launch_bounds__(128, 1)
void esn_fused(const float* __restrict__ u, const float* __restrict__ w_in,
               const float* __restrict__ w_hh, const float* __restrict__ bias,
               float* __restrict__ out) {
    __shared__ unsigned uB[2][TL * UST];    // [buf][l][h] packed hi/lo bf16  34.8 KB
    __shared__ float    pT[2][PBW * PST];   // [wave][p][l] (wave-private)    34.8 KB

    const int t   = threadIdx.x;
    const int bid = blockIdx.x;
    // XCD swizzle: the 8 strip-blocks of one b land on one XCD (u-chunk L2 reuse).
    const int b     = (bid & 7) * 4 + ((bid >> 3) & 3);
    const int strip = bid >> 5;

    const int wv  = t >> 6;        // wave 0/1 -> p-rows [wv*64, wv*64+64)
    const int ln  = t & 63;
    const int n16 = ln & 15;       // MFMA m/n index
    const int q   = ln >> 4;       // MFMA quad (k-group)
    const int pw  = strip * PB + wv * PBW;

    const float* ub_ = u + (size_t)b * (H_ * L_);
    float* const pTw = pT[wv];

    // ---- A-fragments: wave's 4 p-tiles, split bf16 hi/lo, in registers ----
    short8 a_hi[4][2], a_lo[4][2];
    #pragma unroll
    for (int pt = 0; pt < 4; ++pt) {
        const float* wrow = w_in + (size_t)(pw + pt * 16 + n16) * H_;
        #pragma unroll
        for (int s = 0; s < 2; ++s) {
            float v[8];
            *(float4*)&v[0] = *(const float4*)(wrow + s * 32 + q * 8);
            *(float4*)&v[4] = *(const float4*)(wrow + s * 32 + q * 8 + 4);
            #pragma unroll
            for (int j = 0; j < 8; ++j) {
                unsigned ubj = __float_as_uint(v[j]);
                a_hi[pt][s][j] = (short)(ubj >> 16);
                float rm = v[j] - __uint_as_float(ubj & 0xFFFF0000u);
                unsigned r = __float_as_uint(rm);
                r += 0x7FFFu + ((r >> 16) & 1u);
                a_lo[pt][s][j] = (short)(r >> 16);
            }
        }
    }

    // scan state: one p per lane, constants pre-scaled by 2*log2e
    const float d2l  = TWO_LOG2E * w_hh[(size_t)(pw + ln) * (P_ + 1)];
    const float bs2l = TWO_LOG2E * bias[pw + ln];
    float x = 0.0f;

    // staging map: 128 threads, each owns 2 h-rows (a2, a2+1) x 16 l (quarter c)
    const int a2 = (t >> 2) * 2;
    const int c  = t & 3;
    float4 pf0[4], pf1[4];

    auto LOADU = [&](int kk) {
        const float* s0 = ub_ + (size_t)a2 * L_ + (size_t)kk * TL + 16 * c;
        #pragma unroll
        for (int j = 0; j < 4; ++j) {
            pf0[j] = *(const float4*)(s0 + 4 * j);
            pf1[j] = *(const float4*)(s0 + L_ + 4 * j);
        }
    };
    auto STAGE = [&](int bufn) {        // b64 h-pair writes
        unsigned* dst = uB[bufn];
        #pragma unroll
        for (int j = 0; j < 4; ++j) {
            float v0[4], v1[4];
            *(float4*)v0 = pf0[j]; *(float4*)v1 = pf1[j];
            #pragma unroll
            for (int i = 0; i < 4; ++i) {
                const int l = 16 * c + 4 * j + i;
                *(uint2*)&dst[l * UST + a2] =
                    make_uint2(pack_hilo(v0[i]), pack_hilo(v1[i]));
            }
        }
    };
    auto GEMM = [&](int bufn) {         // wave's 64p x 64l, K=64, split bf16
        const unsigned* src = uB[bufn];
        #pragma unroll
        for (int lt = 0; lt < 4; ++lt) {
            const int lb = lt * 16 + n16;
            short8 bh[2], bl[2];
            #pragma unroll
            for (int s = 0; s < 2; ++s) {
                const unsigned* bp = &src[lb * UST + s * 32 + q * 8];
                i32x4 r0 = *(const i32x4*)bp;
                i32x4 r1 = *(const i32x4*)(bp + 4);
                i32x4 fh, fl;
                fh.x = __builtin_amdgcn_perm(r0.y, r0.x, 0x05040100u);
                fh.y = __builtin_amdgcn_perm(r0.w, r0.z, 0x05040100u);
                fh.z = __builtin_amdgcn_perm(r1.y, r1.x, 0x05040100u);
                fh.w = __builtin_amdgcn_perm(r1.w, r1.z, 0x05040100u);
                fl.x = __builtin_amdgcn_perm(r0.y, r0.x, 0x07060302u);
                fl.y = __builtin_amdgcn_perm(r0.w, r0.z, 0x07060302u);
                fl.z = __builtin_amdgcn_perm(r1.y, r1.x, 0x07060302u);
                fl.w = __builtin_amdgcn_perm(r1.w, r1.z, 0x07060302u);
                bh[s] = as_short8(fh);
                bl[s] = as_short8(fl);
            }
            #pragma unroll
            for (int pt = 0; pt < 4; ++pt) {
                f32x4 acc = {0.0f, 0.0f, 0.0f, 0.0f};
                #pragma unroll
                for (int s = 0; s < 2; ++s) {
                    acc = __builtin_amdgcn_mfma_f32_16x16x32_bf16(a_hi[pt][s], bh[s], acc, 0, 0, 0);
                    acc = __builtin_amdgcn_mfma_f32_16x16x32_bf16(a_hi[pt][s], bl[s], acc, 0, 0, 0);
                    acc = __builtin_amdgcn_mfma_f32_16x16x32_bf16(a_lo[pt][s], bh[s], acc, 0, 0, 0);
                }
                // C/D: col(l)=n16, row(p)=pt*16+q*4+r -> b32 scatter (2-way, free)
                #pragma unroll
                for (int r = 0; r < 4; ++r)
                    pTw[(pt * 16 + q * 4 + r) * PST + lb] = acc[r];
            }
        }
    };
    auto SCAN = [&]() {                 // 64 steps in-place on own row (prefetched)
        float* row = pTw + ln * PST;
        float4 va = ((float4*)row)[0], vb = ((float4*)row)[1];
        #pragma unroll
        for (int g = 0; g < 8; ++g) {
            float4 na, nb;
            if (g < 7) { na = ((float4*)row)[2*g + 2]; nb = ((float4*)row)[2*g + 3]; }
            float v0[8] = {va.x, va.y, va.z, va.w, vb.x, vb.y, vb.z, vb.w};
            float xs[8];
            #pragma unroll
            for (int m = 0; m < 8; ++m) {
                const float sv = fmaf(TWO_LOG2E, v0[m], bs2l);             // off-chain
                const float e  = EXP2(fmaf(x, d2l, sv));                   // fma, exp
                x = fmaf(0.5f, x, 0.5f) - __builtin_amdgcn_rcpf(e + 1.0f); // add,rcp,sub
                xs[m] = x;
            }
            ((float4*)row)[2*g]     = make_float4(xs[0], xs[1], xs[2], xs[3]);
            ((float4*)row)[2*g + 1] = make_float4(xs[4], xs[5], xs[6], xs[7]);
            va = na; vb = nb;
        }
    };
    auto WOUT = [&](int kk) {           // coalesced: 16 lanes cover one 256B p-row
        float* ob = out + ((size_t)b * P_ + pw) * L_ + (size_t)kk * TL;
        #pragma unroll
        for (int it = 0; it < 16; ++it) {
            const int i  = it * 64 + ln;
            const int pl = i >> 4;
            const int j4 = (i & 15) * 4;
            float4 o = *(const float4*)(pTw + pl * PST + j4);
            *(float4*)(ob + (size_t)pl * L_ + j4) = o;
        }
    };

    // ---- prologue (k = 0 peeled; hot loop stays branch-free) ----
    LOADU(0);
    STAGE(0);
    __syncthreads();                    // uB[0] ready (both waves)
    LOADU(1);
    GEMM(0);
    STAGE(1);
    SCAN();                             // chunk 0
    __syncthreads();                    // uB[1] ready

    for (int k = 1; k < NCH; ++k) {
        const int buf = k & 1;
        const int kn  = (k + 1 < NCH) ? k + 1 : NCH - 1;  // clamp (uniform select)
        LOADU(kn);                      // global loads drain under GEMM+scan
        WOUT(k - 1);                    // stores retire long before next barrier
        GEMM(buf);                      // reads uB[buf], scatters own pTw
        STAGE(buf ^ 1);                 // k=NCH-1: rewrites stale slot, harmless
        SCAN();                         // chunk k; stall slots filled by above
        __syncthreads();                // uB handoff only (symmetric waves)
    }
    WOUT(NCH - 1);
}

extern "C" void kernel_launch(void* const* d_in, const int* in_sizes, int n_in,
                              void* d_out, int out_size, void* d_ws, size_t ws_size,
                              hipStream_t stream) {
    const float* u    = (const float*)d_in[0];  // [B, H, L]
    const float* w_in = (const float*)d_in[1];  // [P, H]
    const float* w_hh = (const float*)d_in[2];  // [P, P] (diag used)
    const float* bias = (const float*)d_in[3];  // [P]
    float* out = (float*)d_out;                 // [B, P, L]

    dim3 grid(B_ * (P_ / PB));  // 256 blocks = 32 b x 8 strips
    dim3 block(128);            // 2 symmetric waves
    esn_fused<<<grid, block, 0, stream>>>(u, w_in, w_hh, bias, out);
}

// Round 7
// 338.454 us; speedup vs baseline: 1.1413x; 1.1413x over previous
//
#include <hip/hip_runtime.h>
#include <stdint.h>

// ESN fused v9: v3/v5b skeleton + lgkm-only barriers (no store/load drain).
//   __syncthreads() emits s_waitcnt vmcnt(0) lgkmcnt(0) before s_barrier, which
//   serializes ~1.3us of writeout stores + prefetch-load latency into EVERY chunk.
//   LDS hazards only need lgkmcnt(0): stores stay in flight across barriers.
//   phase1: all 4 waves GEMM(k); phase2: wave0 scan(k) || waves1-3 WOUT(k-1)+stage(k+1)
// B=32, D_IN=64, D_STATE=1024, L=2048, LEAK=0.5
#define B_   32
#define H_   64
#define P_   1024
#define L_   2048
#define TL   64
#define PB   64
#define NCH  (L_ / TL)
#define UST  68   // uB row stride in u32 (row = 272 B, 16B-aligned)
#define PST  68   // pT row stride in f32

#define TWO_LOG2E 2.88539008177792681472f

// LDS-only barrier: orders ds ops across waves, leaves global loads/stores in
// flight (loads are waited at register use by compiler-inserted vmcnt(N);
// stores are never read back by this kernel).
#define BARRIER() asm volatile("s_waitcnt lgkmcnt(0)\n\ts_barrier" ::: "memory")

typedef __attribute__((ext_vector_type(8))) short short8;
typedef __attribute__((ext_vector_type(4))) float f32x4;
typedef __attribute__((ext_vector_type(4))) int   i32x4;

// lowers to v_exp_f32 (hardware exp2)
#define EXP2(x) __builtin_exp2f(x)

__device__ __forceinline__ short8 as_short8(i32x4 v) {
    union { i32x4 i; short8 s; } u; u.i = v; return u.s;
}

// f = hi(bf16, trunc) + lo(bf16, RNE of remainder); packed as hi | lo<<16
__device__ __forceinline__ unsigned pack_hilo(float f) {
    unsigned ub = __float_as_uint(f);
    float    fh = __uint_as_float(ub & 0xFFFF0000u);
    float    rm = f - fh;                       // exact
    unsigned r  = __float_as_uint(rm);
    r += 0x7FFFu + ((r >> 16) & 1u);            // RNE to bf16
    return (ub >> 16) | (r & 0xFFFF0000u);
}

// 64 sequential recurrence steps on one p-row in LDS (in-place).
// Next-group prefetch hides ds_read latency; constants pre-scaled by 2*log2e
// so e = exp2(fma(...)) = exp(2*pre). Chain: fma, exp, add, rcp, sub.
__device__ __forceinline__ void scan_row(float* row, float& x,
                                         const float d2l, const float bs2l) {
    float4 va = ((float4*)row)[0], vb = ((float4*)row)[1];
    #pragma unroll
    for (int g = 0; g < 8; ++g) {
        float4 na, nb;
        if (g < 7) { na = ((float4*)row)[2*g + 2]; nb = ((float4*)row)[2*g + 3]; }
        float v0[8] = {va.x, va.y, va.z, va.w, vb.x, vb.y, vb.z, vb.w};
        float xs[8];
        #pragma unroll
        for (int m = 0; m < 8; ++m) {
            const float sv = fmaf(TWO_LOG2E, v0[m], bs2l);             // off-chain
            const float e  = EXP2(fmaf(x, d2l, sv));                   // fma, exp
            x = fmaf(0.5f, x, 0.5f) - __builtin_amdgcn_rcpf(e + 1.0f); // add,rcp,sub
            xs[m] = x;
        }
        ((float4*)row)[2*g]     = make_float4(xs[0], xs[1], xs[2], xs[3]);
        ((float4*)row)[2*g + 1] = make_float4(xs[4], xs[5], xs[6], xs[7]);
        va = na; vb = nb;
    }
}

__global__ __launch_bounds__(256, 2)
void esn_fused(const float* __restrict__ u, const float* __restrict__ w_in,
               const float* __restrict__ w_hh, const float* __restrict__ bias,
               float* __restrict__ out) {
    __shared__ unsigned uB[TL * UST];      // [l][h] packed hi/lo bf16   17.4 KB
    __shared__ float    pT[2][PB * PST];   // [p][l]                     34.8 KB

    const int t   = threadIdx.x;
    const int bid = blockIdx.x;
    const int s_  = bid >> 3;                       // XCD swizzle: same-b on one XCD
    const int b   = ((s_ >> 4) << 3) | (bid & 7);
    const int p0  = (s_ & 15) * PB;

    const int wv  = t >> 6;        // wave 0..3 -> p-strip wv*16
    const int ln  = t & 63;
    const int n16 = ln & 15;       // MFMA m/n index
    const int q   = ln >> 4;       // MFMA quad (k-group)

    // ---- A-fragments: w_in rows, split bf16 hi/lo, held in registers ----
    short8 a_hi[2], a_lo[2];
    {
        const float* wrow = w_in + (size_t)(p0 + wv * 16 + n16) * H_;
        #pragma unroll
        for (int s = 0; s < 2; ++s) {
            float v[8];
            *(float4*)&v[0] = *(const float4*)(wrow + s * 32 + q * 8);
            *(float4*)&v[4] = *(const float4*)(wrow + s * 32 + q * 8 + 4);
            #pragma unroll
            for (int j = 0; j < 8; ++j) {
                unsigned ub = __float_as_uint(v[j]);
                a_hi[s][j] = (short)(ub >> 16);
                float rm = v[j] - __uint_as_float(ub & 0xFFFF0000u);
                unsigned r = __float_as_uint(rm);
                r += 0x7FFFu + ((r >> 16) & 1u);
                a_lo[s][j] = (short)(r >> 16);
            }
        }
    }

    // scan state (wave 0, one p per lane) — constants pre-scaled by 2*log2e
    float x = 0.0f, d2l = 0.0f, bs2l = 0.0f;
    if (t < PB) {
        d2l  = TWO_LOG2E * w_hh[(size_t)(p0 + t) * (P_ + 1)];
        bs2l = TWO_LOG2E * bias[p0 + t];
    }

    // staging maps (threads 64..255): jobA rows 16..63, jobB (t<128) rows 0..15
    const int  hA   = t >> 2;            // 16..63 for t>=64
    const int  cA   = t & 3;
    const bool jobB = (t >= 64 && t < 128);
    const int  hB   = (t - 64) >> 2;     // 0..15
    const float* ub_ = u + (size_t)b * (H_ * L_);

    float4 pfA[4], pfB[4];

    // ---- prologue: load + stage chunk 0 ----
    if (t >= 64) {
        #pragma unroll
        for (int j = 0; j < 4; ++j)
            pfA[j] = *(const float4*)(ub_ + (size_t)hA * L_ + 16 * j + 4 * cA);
        if (jobB)
            #pragma unroll
            for (int j = 0; j < 4; ++j)
                pfB[j] = *(const float4*)(ub_ + (size_t)hB * L_ + 16 * j + 4 * cA);
        #pragma unroll
        for (int j = 0; j < 4; ++j) {
            const int l = 16 * j + 4 * cA;
            uB[(l + 0) * UST + hA] = pack_hilo(pfA[j].x);
            uB[(l + 1) * UST + hA] = pack_hilo(pfA[j].y);
            uB[(l + 2) * UST + hA] = pack_hilo(pfA[j].z);
            uB[(l + 3) * UST + hA] = pack_hilo(pfA[j].w);
        }
        if (jobB)
            #pragma unroll
            for (int j = 0; j < 4; ++j) {
                const int l = 16 * j + 4 * cA;
                uB[(l + 0) * UST + hB] = pack_hilo(pfB[j].x);
                uB[(l + 1) * UST + hB] = pack_hilo(pfB[j].y);
                uB[(l + 2) * UST + hB] = pack_hilo(pfB[j].z);
                uB[(l + 3) * UST + hB] = pack_hilo(pfB[j].w);
            }
    }
    BARRIER();

    for (int k = 0; k < NCH; ++k) {
        const int buf = k & 1;
        const int kn  = (k + 1 < NCH) ? k + 1 : k;

        // ---- prefetch next u chunk into registers (drains under GEMM) ----
        if (t >= 64) {
            #pragma unroll
            for (int j = 0; j < 4; ++j)
                pfA[j] = *(const float4*)(ub_ + (size_t)hA * L_ + kn * TL + 16 * j + 4 * cA);
            if (jobB)
                #pragma unroll
                for (int j = 0; j < 4; ++j)
                    pfB[j] = *(const float4*)(ub_ + (size_t)hB * L_ + kn * TL + 16 * j + 4 * cA);
        }

        // ---- MFMA GEMM: 64p x 64l, K=64, split bf16 (3 products) ----
        #pragma unroll
        for (int jt = 0; jt < 4; ++jt) {
            f32x4 acc = {0.0f, 0.0f, 0.0f, 0.0f};
            #pragma unroll
            for (int s = 0; s < 2; ++s) {
                const unsigned* bp = &uB[(jt * 16 + n16) * UST + s * 32 + q * 8];
                i32x4 r0 = *(const i32x4*)bp;
                i32x4 r1 = *(const i32x4*)(bp + 4);
                i32x4 fh, fl;
                fh.x = __builtin_amdgcn_perm(r0.y, r0.x, 0x05040100u);
                fh.y = __builtin_amdgcn_perm(r0.w, r0.z, 0x05040100u);
                fh.z = __builtin_amdgcn_perm(r1.y, r1.x, 0x05040100u);
                fh.w = __builtin_amdgcn_perm(r1.w, r1.z, 0x05040100u);
                fl.x = __builtin_amdgcn_perm(r0.y, r0.x, 0x07060302u);
                fl.y = __builtin_amdgcn_perm(r0.w, r0.z, 0x07060302u);
                fl.z = __builtin_amdgcn_perm(r1.y, r1.x, 0x07060302u);
                fl.w = __builtin_amdgcn_perm(r1.w, r1.z, 0x07060302u);
                short8 bh = as_short8(fh), bl = as_short8(fl);
                acc = __builtin_amdgcn_mfma_f32_16x16x32_bf16(a_hi[s], bh, acc, 0, 0, 0);
                acc = __builtin_amdgcn_mfma_f32_16x16x32_bf16(a_hi[s], bl, acc, 0, 0, 0);
                acc = __builtin_amdgcn_mfma_f32_16x16x32_bf16(a_lo[s], bh, acc, 0, 0, 0);
            }
            // C/D: col(l) = lane&15, row(p) = quad*4 + r  -> scatter b32, 2-way max
            #pragma unroll
            for (int r = 0; r < 4; ++r)
                pT[buf][(wv * 16 + q * 4 + r) * PST + jt * 16 + n16] = acc[r];
        }
        BARRIER();   // A: pT[buf] complete; uB reads done (lgkm only)

        if (t < PB) {
            // ---- scan 64 steps in-place on own row ----
            scan_row(&pT[buf][t * PST], x, d2l, bs2l);
        } else {
            // ---- WOUT(k-1) first: stores issue early, drain under next GEMM ----
            if (k > 0) {
                const float* pbase = pT[1 - buf];
                float* ob = out + (size_t)b * (P_ * L_) + (size_t)p0 * L_ + (size_t)(k - 1) * TL;
                for (int i = t - 64; i < 1024; i += 192) {
                    const int p = i >> 4, j = i & 15;
                    float4 o = *(const float4*)(pbase + p * PST + 4 * j);
                    *(float4*)(ob + (size_t)p * L_ + 4 * j) = o;
                }
            }
            // ---- stage uB for chunk k+1 ----
            #pragma unroll
            for (int j = 0; j < 4; ++j) {
                const int l = 16 * j + 4 * cA;
                uB[(l + 0) * UST + hA] = pack_hilo(pfA[j].x);
                uB[(l + 1) * UST + hA] = pack_hilo(pfA[j].y);
                uB[(l + 2) * UST + hA] = pack_hilo(pfA[j].z);
                uB[(l + 3) * UST + hA] = pack_hilo(pfA[j].w);
            }
            if (jobB)
                #pragma unroll
                for (int j = 0; j < 4; ++j) {
                    const int l = 16 * j + 4 * cA;
                    uB[(l + 0) * UST + hB] = pack_hilo(pfB[j].x);
                    uB[(l + 1) * UST + hB] = pack_hilo(pfB[j].y);
                    uB[(l + 2) * UST + hB] = pack_hilo(pfB[j].z);
                    uB[(l + 3) * UST + hB] = pack_hilo(pfB[j].w);
                }
        }
        BARRIER();   // B: scan + stage done; WOUT ds_reads done (stores in flight)
    }

    // ---- epilogue: write out last chunk (all 256 threads) ----
    {
        const int buf = (NCH - 1) & 1;
        const float* pbase = pT[buf];
        float* ob = out + (size_t)b * (P_ * L_) + (size_t)p0 * L_ + (size_t)(NCH - 1) * TL;
        for (int i = t; i < 1024; i += 256) {
            const int p = i >> 4, j = i & 15;
            float4 o = *(const float4*)(pbase + p * PST + 4 * j);
            *(float4*)(ob + (size_t)p * L_ + 4 * j) = o;
        }
    }
}

extern "C" void kernel_launch(void* const* d_in, const int* in_sizes, int n_in,
                              void* d_out, int out_size, void* d_ws, size_t ws_size,
                              hipStream_t stream) {
    const float* u    = (const float*)d_in[0];  // [B, H, L]
    const float* w_in = (const float*)d_in[1];  // [P, H]
    const float* w_hh = (const float*)d_in[2];  // [P, P] (diag used)
    const float* bias = (const float*)d_in[3];  // [P]
    float* out = (float*)d_out;                 // [B, P, L]

    dim3 grid(B_ * (P_ / PB));  // 512 blocks
    dim3 block(256);
    esn_fused<<<grid, block, 0, stream>>>(u, w_in, w_hh, bias, out);
}